// Round 5
// baseline (88.578 us; speedup 1.0000x reference)
//
#include <hip/hip_runtime.h>

typedef float f32x4 __attribute__((ext_vector_type(4)));

// Round-4 structure exactly, ONE change: stores are now ALSO non-temporal.
// (Round 2's NT-store regression was confounded with a grid-stride loop;
// with NT loads in place the isolated effect of no-allocate writes on a
// touch-once stream is worth one A/B.)
//
// Grid: y = batch (16), x = per4 / 512 = 2048 blocks of 256 threads.
__global__ void __launch_bounds__(256) rot_apply2ntb(
        const f32x4* __restrict__ in,
        f32x4* __restrict__ out,
        const float* __restrict__ theta,
        const float* __restrict__ phi,
        int per4) {
    const int b = blockIdx.y;

    float st, ct, sp, cp;
    sincosf(theta[b], &st, &ct);
    sincosf(phi[b],   &sp, &cp);

    const long long base = (long long)b * per4;
    const int i0 = blockIdx.x * (blockDim.x * 2) + threadIdx.x;
    const int i1 = i0 + blockDim.x;

    f32x4 v0, v1;
    bool ok0 = i0 < per4, ok1 = i1 < per4;
    if (ok0) v0 = __builtin_nontemporal_load(&in[base + i0]);
    if (ok1) v1 = __builtin_nontemporal_load(&in[base + i1]);

    if (ok0) {
        f32x4 o;
        o.x =  v0.x * ct + v0.y * st;
        o.y = -v0.x * st + v0.y * ct;
        o.z =  v0.z * cp + v0.w * sp;
        o.w = -v0.z * sp + v0.w * cp;
        __builtin_nontemporal_store(o, &out[base + i0]);
    }
    if (ok1) {
        f32x4 o;
        o.x =  v1.x * ct + v1.y * st;
        o.y = -v1.x * st + v1.y * ct;
        o.z =  v1.z * cp + v1.w * sp;
        o.w = -v1.z * sp + v1.w * cp;
        __builtin_nontemporal_store(o, &out[base + i1]);
    }
}

extern "C" void kernel_launch(void* const* d_in, const int* in_sizes, int n_in,
                              void* d_out, int out_size, void* d_ws, size_t ws_size,
                              hipStream_t stream) {
    const float* emb   = (const float*)d_in[0];
    const float* theta = (const float*)d_in[1];
    const float* phi   = (const float*)d_in[2];
    float* out = (float*)d_out;

    int B = in_sizes[1];                       // theta has B elements
    long long total = (long long)in_sizes[0];  // B*N*D
    long long per_batch = total / B;           // N*D
    int per4 = (int)(per_batch / 4);           // float4 blocks per batch

    const int threads = 256;
    const int per_block = threads * 2;         // 2 float4 per thread
    int blocksX = (per4 + per_block - 1) / per_block;

    dim3 grid(blocksX, B);
    rot_apply2ntb<<<grid, threads, 0, stream>>>(
        (const f32x4*)emb, (f32x4*)out, theta, phi, per4);
}

// Round 6
// 82.886 us; speedup vs baseline: 1.0687x; 1.0687x over previous
//
#include <hip/hip_runtime.h>

typedef float f32x4 __attribute__((ext_vector_type(4)));

// FINAL (revert to round-4 optimum): NT loads + normal stores.
// - NT loads: touch-once 256 MiB read stream must not allocate in L2/L3
//   (isolated A/B: 97.7 -> 82.7 us).
// - Normal stores: L2 write-coalescing needs allocation (NT stores isolated
//   A/B: 82.7 -> 88.6 us regression).
// - Per-block wave-uniform sincos fused in (no separate precompute launch).
// - 2 independent float4 per thread, no grid-stride loop (loop regressed r2).
//
// Grid: y = batch (16), x = per4 / 512 = 2048 blocks of 256 threads.
__global__ void __launch_bounds__(256) rot_apply2nt(
        const f32x4* __restrict__ in,
        f32x4* __restrict__ out,
        const float* __restrict__ theta,
        const float* __restrict__ phi,
        int per4) {
    const int b = blockIdx.y;

    float st, ct, sp, cp;
    sincosf(theta[b], &st, &ct);
    sincosf(phi[b],   &sp, &cp);

    const long long base = (long long)b * per4;
    const int i0 = blockIdx.x * (blockDim.x * 2) + threadIdx.x;
    const int i1 = i0 + blockDim.x;

    f32x4 v0, v1;
    bool ok0 = i0 < per4, ok1 = i1 < per4;
    if (ok0) v0 = __builtin_nontemporal_load(&in[base + i0]);
    if (ok1) v1 = __builtin_nontemporal_load(&in[base + i1]);

    if (ok0) {
        f32x4 o;
        o.x =  v0.x * ct + v0.y * st;
        o.y = -v0.x * st + v0.y * ct;
        o.z =  v0.z * cp + v0.w * sp;
        o.w = -v0.z * sp + v0.w * cp;
        out[base + i0] = o;
    }
    if (ok1) {
        f32x4 o;
        o.x =  v1.x * ct + v1.y * st;
        o.y = -v1.x * st + v1.y * ct;
        o.z =  v1.z * cp + v1.w * sp;
        o.w = -v1.z * sp + v1.w * cp;
        out[base + i1] = o;
    }
}

extern "C" void kernel_launch(void* const* d_in, const int* in_sizes, int n_in,
                              void* d_out, int out_size, void* d_ws, size_t ws_size,
                              hipStream_t stream) {
    const float* emb   = (const float*)d_in[0];
    const float* theta = (const float*)d_in[1];
    const float* phi   = (const float*)d_in[2];
    float* out = (float*)d_out;

    int B = in_sizes[1];                       // theta has B elements
    long long total = (long long)in_sizes[0];  // B*N*D
    long long per_batch = total / B;           // N*D
    int per4 = (int)(per_batch / 4);           // float4 blocks per batch

    const int threads = 256;
    const int per_block = threads * 2;         // 2 float4 per thread
    int blocksX = (per4 + per_block - 1) / per_block;

    dim3 grid(blocksX, B);
    rot_apply2nt<<<grid, threads, 0, stream>>>(
        (const f32x4*)emb, (f32x4*)out, theta, phi, per4);
}